// Round 6
// baseline (482.566 us; speedup 1.0000x reference)
//
#include <hip/hip_runtime.h>
#include <hip/hip_bf16.h>

// R5. Bench R4: PASSED 401us. feats tile_mfma = 114us @ 25% HBM, MfmaUtil 10%,
// VALU 15%, occ 39% -> latency-bound (traffic is now ideal: WRITE 147MB,
// FETCH 75MB w/ L3 help; floor ~48us). Exposed latency: (1) one tile per
// block -> stage barrier eats full HBM latency; (2) 64 global B-frag loads
// per wave-tile from L2 in the k-loop (~1.2GB L2 traffic).
// Fix: grid-stride multi-tile + T14 register prefetch of next A-tile;
// B-hi staged in LDS once per block (32KB, amortized over 9 tiles);
// B-lo stays global (halved L2 pressure). Also fold W_g into ucontrib
// weight (Wgr = WR@Wg) so uc comes straight from mean_t(x).

constexpr int T_ = 4, E_ = 4096, B_ = 2, D_ = 128, N_ = 384;
constexpr int EB = E_ * B_;                  // 8192 (e,b) pairs
constexpr int XSTRIDE_T = E_ * B_ * D_;      // floats between t-planes
constexpr int XROWS = T_ * EB;               // 32768 rows of x
constexpr int NROWS = N_ * N_ * B_;          // 294912 feats rows
constexpr int NCELLS = N_ * N_;              // 147456

typedef __attribute__((ext_vector_type(8))) short bf16x8;
typedef __attribute__((ext_vector_type(4))) float f32x4;
union BF8 { bf16x8 v; ushort u[8]; };

// workspace layout (float element offsets)
constexpr size_t OFF_WTG    = 0;                              // 16384
constexpr size_t OFF_WTL    = 16384;                          // 16384
constexpr size_t OFF_WTR    = 32768;                          // 16384
constexpr size_t OFF_BCOMB  = 49152;                          // 128
constexpr size_t OFF_BP     = 49280;                          // 128
constexpr size_t OFF_XMEAN  = 49408;                          // EB*D
constexpr size_t OFF_UC     = OFF_XMEAN + (size_t)EB * D_;    // EB*D
constexpr size_t OFF_WIN    = OFF_UC + (size_t)EB * D_;       // N*N ints
constexpr size_t OFF_BPACK  = OFF_WIN + (size_t)NCELLS;       // 16384 (64KB)
constexpr size_t OFF_BPACKG = OFF_BPACK + 16384;              // 16384
constexpr size_t OFF_BPACKR = OFF_BPACKG + 16384;             // 16384
constexpr size_t OFF_WGR    = OFF_BPACKR + 16384;             // 16384
constexpr size_t OFF_BGR    = OFF_WGR + 16384;                // 128
constexpr size_t WS_FLOATS  = OFF_BGR + 128;                  // ~9.5MB

static __device__ inline ushort f2bf(float x) {
  const uint u = __float_as_uint(x);
  return (ushort)((u + 0x7fffu + ((u >> 16) & 1u)) >> 16);
}
static __device__ inline float bf2f(ushort h) {
  return __uint_as_float(((uint)h) << 16);
}

// ---------------------------------------------------------------------------
// prep: W_comb halves (transposed), W_g transpose, bcomb, bp, winner init
// ---------------------------------------------------------------------------
__global__ __launch_bounds__(256) void prep_kernel(
    const float* __restrict__ W_f, const float* __restrict__ W_lin,
    const float* __restrict__ W_g, const float* __restrict__ b_lin,
    const float* __restrict__ b_f, const float* __restrict__ pad,
    float* __restrict__ WtG, float* __restrict__ WtL, float* __restrict__ WtR,
    float* __restrict__ bcomb, float* __restrict__ bp, int* __restrict__ winner) {
  const int o = blockIdx.x;    // 0..127
  const int c = threadIdx.x;   // 0..255

  for (int i = blockIdx.x * 256 + c; i < NCELLS; i += 128 * 256) winner[i] = -1;

  float acc = 0.f;
#pragma unroll 4
  for (int d = 0; d < D_; ++d) acc += W_f[o * D_ + d] * W_lin[d * (2 * D_) + c];

  if (c < D_) {
    WtL[c * D_ + o] = acc;
    WtG[c * D_ + o] = W_g[o * D_ + c];
  } else {
    WtR[(c - D_) * D_ + o] = acc;
  }

  __shared__ float red[256];
  red[c] = (c >= D_) ? acc : 0.f;
  __syncthreads();
  for (int s = 128; s > 0; s >>= 1) {
    if (c < s) red[c] += red[c + s];
    __syncthreads();
  }
  const float padsum = red[0];
  __syncthreads();
  red[c] = (c < D_) ? W_f[o * D_ + c] * b_lin[c] : 0.f;
  __syncthreads();
  for (int s = 128; s > 0; s >>= 1) {
    if (c < s) red[c] += red[c + s];
    __syncthreads();
  }
  if (c == 0) {
    const float bc = b_f[o] + red[0];
    bcomb[o] = bc;
    bp[o] = bc + pad[0] * padsum;
  }
}

// ---------------------------------------------------------------------------
// prepB: Wgr_kn[c*128+o] = sum_d WtR[d*128+o] * W_g[d*128+c]
//        bgr[o]          = sum_d WtR[d*128+o] * b_g[d]
// (folds gemm1's W_g into the ucontrib weight so uc = mean_t(x) @ Wgr + bgr)
// grid: 128 blocks (o) x 128 thr (c)
// ---------------------------------------------------------------------------
__global__ __launch_bounds__(128) void prepB_kernel(
    const float* __restrict__ WtR, const float* __restrict__ W_g,
    const float* __restrict__ b_g, float* __restrict__ Wgr_kn,
    float* __restrict__ bgr) {
  const int o = blockIdx.x;
  const int c = threadIdx.x;
  float acc = 0.f;
#pragma unroll 4
  for (int d = 0; d < D_; ++d) acc += WtR[d * D_ + o] * W_g[d * D_ + c];
  Wgr_kn[c * D_ + o] = acc;

  __shared__ float red[128];
  red[c] = WtR[c * D_ + o] * b_g[c];
  __syncthreads();
  for (int s = 64; s > 0; s >>= 1) {
    if (c < s) red[c] += red[c + s];
    __syncthreads();
  }
  if (c == 0) bgr[o] = red[0];
}

// ---------------------------------------------------------------------------
// prep2: pack a [k][n] fp32 weight (128x128) into bf16 hi/lo MFMA B-fragment
// per-lane order. Frag fi = hi*32 + k0*8 + n0 (fi<32 = hi half).
// ---------------------------------------------------------------------------
__global__ __launch_bounds__(64) void prep2_kernel(
    const float* __restrict__ Wkn, ushort* __restrict__ Bpack) {
  const int fi = blockIdx.x;          // 0..63
  const int l = threadIdx.x;          // 0..63
  const int ishi = (fi >> 5) ^ 1;     // fi<32 -> hi
  const int k0 = (fi >> 3) & 3;
  const int n0 = fi & 7;
  const int o = n0 * 16 + (l & 15);
  const int kb = k0 * 32 + ((l >> 4) & 3) * 8;
  ushort* dst = Bpack + ((size_t)fi * 64 + l) * 8;
#pragma unroll
  for (int j = 0; j < 8; ++j) {
    const float w = Wkn[(size_t)(kb + j) * D_ + o];
    const ushort h = f2bf(w);
    if (ishi) {
      dst[j] = h;
    } else {
      dst[j] = f2bf(w - bf2f(h));
    }
  }
}

// ---------------------------------------------------------------------------
// scatter: last-e-wins per grid cell (deterministic via atomicMax on e)
// ---------------------------------------------------------------------------
__global__ __launch_bounds__(256) void scatter_kernel(
    const int* __restrict__ nodes, int* __restrict__ winner) {
  const int e = blockIdx.x * 256 + threadIdx.x;
  if (e < E_) {
    const int n0 = nodes[e * 2 + 0];
    const int n1 = nodes[e * 2 + 1];
    atomicMax(&winner[(n0 - 1) * N_ + (n1 - 1)], e);
  }
}

// ---------------------------------------------------------------------------
// tile_mfma v2: out[r][o] = A[r][:] . Wpack[:][o] + bias[o]
// 256 thr = 4 waves; 64-row tiles, grid-stride w/ register prefetch (T14).
// LDS: lA 32KB (A tile, XOR-swizzled; reused for C transpose)
//      lBhi 32KB (hi-half B frags, staged once per block).
// B-lo frags read per-k0 from L2-hot Bpack.
// ---------------------------------------------------------------------------
__global__ __launch_bounds__(256) void tile_mfma_kernel(
    const float* __restrict__ A, const ushort* __restrict__ Bpack,
    const float* __restrict__ bias, float* __restrict__ out, int ntiles) {
  __shared__ float lA[64 * 128];    // 32 KB (A tile, then C)
  __shared__ bf16x8 lBhi[2048];     // 32 KB (frags 0..31 = hi)
  const int tid = threadIdx.x;
  const int stride = gridDim.x;

  {  // stage B-hi once per block
    const bf16x8* src = (const bf16x8*)Bpack;
    for (int i = tid; i < 2048; i += 256) lBhi[i] = src[i];
  }

  const int wave = tid >> 6, lane = tid & 63;
  const int l15 = lane & 15;
  const int lh = (lane >> 4) & 3;
  const int arow = wave * 16 + l15;
  const int asw = (arow & 7) << 2;
  const bf16x8* __restrict__ bp8 = (const bf16x8*)Bpack;

  float bs8[8];
#pragma unroll
  for (int n0 = 0; n0 < 8; ++n0) bs8[n0] = bias ? bias[n0 * 16 + l15] : 0.f;

  int tile = blockIdx.x;
  float4 pf[8];
  if (tile < ntiles) {
    const size_t t0 = (size_t)tile * 64;
#pragma unroll
    for (int j = 0; j < 8; ++j) {
      const int idx = j * 256 + tid;
      pf[j] = *(const float4*)&A[(t0 + (idx >> 5)) * D_ + (idx & 31) * 4];
    }
  }

  for (; tile < ntiles; tile += stride) {
    const size_t tile0 = (size_t)tile * 64;
    __syncthreads();   // prev C reads done (also covers B-hi stage, iter 0)
#pragma unroll
    for (int j = 0; j < 8; ++j) {
      const int idx = j * 256 + tid;
      const int row = idx >> 5, c4 = idx & 31;
      *(float4*)&lA[(row * 128 + c4 * 4) ^ ((row & 7) << 2)] = pf[j];
    }
    __syncthreads();   // A visible

    const int next = tile + stride;
    if (next < ntiles) {   // T14: issue next tile's loads, no wait
      const size_t t0 = (size_t)next * 64;
#pragma unroll
      for (int j = 0; j < 8; ++j) {
        const int idx = j * 256 + tid;
        pf[j] = *(const float4*)&A[(t0 + (idx >> 5)) * D_ + (idx & 31) * 4];
      }
    }

    f32x4 acc[8];
#pragma unroll
    for (int n0 = 0; n0 < 8; ++n0) {
      acc[n0][0] = bs8[n0]; acc[n0][1] = bs8[n0];
      acc[n0][2] = bs8[n0]; acc[n0][3] = bs8[n0];
    }

#pragma unroll
    for (int k0 = 0; k0 < 4; ++k0) {
      // B-lo from global (L2-hot), issued early to hide under MFMAs
      bf16x8 bl[8];
#pragma unroll
      for (int n0 = 0; n0 < 8; ++n0)
        bl[n0] = bp8[(size_t)((32 + k0 * 8 + n0) * 64 + lane)];
      const int base = arow * 128 + lh * 8 + k0 * 32;
      const float4 a0 = *(const float4*)&lA[(base + 0) ^ asw];
      const float4 a1 = *(const float4*)&lA[(base + 4) ^ asw];
      const float xs[8] = {a0.x, a0.y, a0.z, a0.w, a1.x, a1.y, a1.z, a1.w};
      BF8 ah, al;
#pragma unroll
      for (int j = 0; j < 8; ++j) {
        const ushort h = f2bf(xs[j]);
        ah.u[j] = h;
        al.u[j] = f2bf(xs[j] - bf2f(h));
      }
      bf16x8 bh[8];
#pragma unroll
      for (int n0 = 0; n0 < 8; ++n0)
        bh[n0] = lBhi[(k0 * 8 + n0) * 64 + lane];
#pragma unroll
      for (int n0 = 0; n0 < 8; ++n0) {
        acc[n0] = __builtin_amdgcn_mfma_f32_16x16x32_bf16(ah.v, bh[n0], acc[n0], 0, 0, 0);
        acc[n0] = __builtin_amdgcn_mfma_f32_16x16x32_bf16(al.v, bh[n0], acc[n0], 0, 0, 0);
      }
#pragma unroll
      for (int n0 = 0; n0 < 8; ++n0)
        acc[n0] = __builtin_amdgcn_mfma_f32_16x16x32_bf16(ah.v, bl[n0], acc[n0], 0, 0, 0);
    }

    __syncthreads();   // all waves done reading A
#pragma unroll
    for (int n0 = 0; n0 < 8; ++n0) {
      const int col = n0 * 16 + l15;
#pragma unroll
      for (int i = 0; i < 4; ++i) {
        const int row = wave * 16 + lh * 4 + i;
        lA[(row * 128 + col) ^ ((row & 7) << 2)] = acc[n0][i];
      }
    }
    __syncthreads();   // C visible
#pragma unroll
    for (int j = 0; j < 8; ++j) {
      const int idx = j * 256 + tid;
      const int row = idx >> 5, c4 = idx & 31;
      const float4 v =
          *(const float4*)&lA[(row * 128 + c4 * 4) ^ ((row & 7) << 2)];
      *(float4*)&out[(tile0 + row) * D_ + c4 * 4] = v;
    }
  }
}

// ---------------------------------------------------------------------------
// mean over t of x: xmean[pair][c] = 0.25 * sum_t x[t*EB + pair][c]
// ---------------------------------------------------------------------------
__global__ __launch_bounds__(256) void mean_kernel(
    const float* __restrict__ x, float* __restrict__ xmean) {
  const int idx = blockIdx.x * 256 + threadIdx.x;   // 0 .. EB*32-1
  const int pair = idx >> 5;
  const int o4 = (idx & 31) * 4;
  const size_t base = (size_t)pair * D_ + o4;
  float4 s = *(const float4*)&x[base];
  const float4 v1 = *(const float4*)&x[base + (size_t)1 * XSTRIDE_T];
  const float4 v2 = *(const float4*)&x[base + (size_t)2 * XSTRIDE_T];
  const float4 v3 = *(const float4*)&x[base + (size_t)3 * XSTRIDE_T];
  s.x = (s.x + v1.x + v2.x + v3.x) * 0.25f;
  s.y = (s.y + v1.y + v2.y + v3.y) * 0.25f;
  s.z = (s.z + v1.z + v2.z + v3.z) * 0.25f;
  s.w = (s.w + v1.w + v2.w + v3.w) * 0.25f;
  *(float4*)&xmean[base] = s;
}

// ---------------------------------------------------------------------------
// fixup: winner rows: out_feats[cell*2+b][o] += uc[e*2+b][o] + bcomb[o]-bp[o]
// ---------------------------------------------------------------------------
__global__ __launch_bounds__(256) void fixup_kernel(
    const int* __restrict__ nodes, const int* __restrict__ winner,
    const float* __restrict__ uc, const float* __restrict__ bcomb,
    const float* __restrict__ bp, float* __restrict__ out_feats) {
  const int e = blockIdx.x;
  const int n0 = nodes[e * 2 + 0] - 1;
  const int n1 = nodes[e * 2 + 1] - 1;
  const int cell = n0 * N_ + n1;
  if (winner[cell] != e) return;
  const int t = threadIdx.x;
  const int b = t >> 7, o = t & 127;
  out_feats[((size_t)cell * 2 + b) * D_ + o] +=
      uc[((size_t)e * 2 + b) * D_ + o] + bcomb[o] - bp[o];
}

// ---------------------------------------------------------------------------
// gather_add: out_x[t,e,b,:] += out_feats[n0-1, n1-1, b, :]
// ---------------------------------------------------------------------------
__global__ __launch_bounds__(256) void gather_add_kernel(
    const int* __restrict__ nodes, const float* __restrict__ out_feats,
    float* __restrict__ out_x) {
  const int e = blockIdx.x;
  const int tid = threadIdx.x;
  const int b = tid >> 7, o = tid & 127;
  const int n0 = nodes[((size_t)b * E_ + e) * 2 + 0] - 1;
  const int n1 = nodes[((size_t)b * E_ + e) * 2 + 1] - 1;
  const float fs = out_feats[(((size_t)n0 * N_ + n1) * B_ + b) * D_ + o];
#pragma unroll
  for (int t = 0; t < T_; ++t)
    out_x[(((size_t)t * E_ + e) * B_ + b) * D_ + o] += fs;
}

// ---------------------------------------------------------------------------
extern "C" void kernel_launch(void* const* d_in, const int* in_sizes, int n_in,
                              void* d_out, int out_size, void* d_ws, size_t ws_size,
                              hipStream_t stream) {
  const float* x      = (const float*)d_in[0];
  const float* feats  = (const float*)d_in[1];
  const int*   nodes  = (const int*)d_in[2];
  const float* pad    = (const float*)d_in[5];
  const float* W_g    = (const float*)d_in[6];
  const float* b_g    = (const float*)d_in[7];
  const float* W_lin  = (const float*)d_in[8];
  const float* b_lin  = (const float*)d_in[9];
  const float* W_f    = (const float*)d_in[10];
  const float* b_f    = (const float*)d_in[11];

  float* out_x     = (float*)d_out;                       // T*E*B*D
  float* out_feats = out_x + (size_t)T_ * E_ * B_ * D_;   // N*N*B*D

  if (ws_size < WS_FLOATS * sizeof(float) + 16) return;

  float*  wsf    = (float*)d_ws;
  float*  WtG    = wsf + OFF_WTG;
  float*  WtL    = wsf + OFF_WTL;
  float*  WtR    = wsf + OFF_WTR;
  float*  bcomb  = wsf + OFF_BCOMB;
  float*  bpv    = wsf + OFF_BP;
  float*  xmean  = wsf + OFF_XMEAN;
  float*  uc     = wsf + OFF_UC;
  int*    win    = (int*)(wsf + OFF_WIN);
  ushort* Bpack  = (ushort*)(wsf + OFF_BPACK);
  ushort* BpackG = (ushort*)(wsf + OFF_BPACKG);
  ushort* BpackR = (ushort*)(wsf + OFF_BPACKR);
  float*  WgrKn  = wsf + OFF_WGR;
  float*  bgr    = wsf + OFF_BGR;

  prep_kernel<<<dim3(128), dim3(256), 0, stream>>>(W_f, W_lin, W_g, b_lin, b_f,
                                                   pad, WtG, WtL, WtR, bcomb,
                                                   bpv, win);
  prepB_kernel<<<dim3(128), dim3(128), 0, stream>>>(WtR, W_g, b_g, WgrKn, bgr);
  prep2_kernel<<<dim3(64), dim3(64), 0, stream>>>(WtL, Bpack);
  prep2_kernel<<<dim3(64), dim3(64), 0, stream>>>(WtG, BpackG);
  prep2_kernel<<<dim3(64), dim3(64), 0, stream>>>(WgrKn, BpackR);
  scatter_kernel<<<dim3(E_ / 256), dim3(256), 0, stream>>>(nodes, win);
  mean_kernel<<<dim3(EB * 32 / 256), dim3(256), 0, stream>>>(x, xmean);

  // x1 = x @ W_g^T + b_g   (32768 rows -> 512 tiles)
  tile_mfma_kernel<<<dim3(512), dim3(256), 0, stream>>>(x, BpackG, b_g, out_x,
                                                        XROWS / 64);
  // uc = mean_t(x) @ Wgr^T + bgr   (8192 rows -> 128 tiles)
  tile_mfma_kernel<<<dim3(128), dim3(256), 0, stream>>>(xmean, BpackR, bgr, uc,
                                                        EB / 64);
  // feats2 = feats @ Wcomb_left^T + bp   (294912 rows -> 4608 tiles, 9/block)
  tile_mfma_kernel<<<dim3(512), dim3(256), 0, stream>>>(feats, Bpack, bpv,
                                                        out_feats, NROWS / 64);
  fixup_kernel<<<dim3(E_), dim3(256), 0, stream>>>(nodes, win, uc, bcomb, bpv,
                                                   out_feats);
  gather_add_kernel<<<dim3(E_), dim3(256), 0, stream>>>(nodes, out_feats,
                                                        out_x);
}

// Round 7
// 443.795 us; speedup vs baseline: 1.0874x; 1.0874x over previous
//
#include <hip/hip_runtime.h>
#include <hip/hip_bf16.h>

// R6. R5 REGRESSED (483us; feats 178us): 64KB LDS + 148 VGPR -> occ 11%
// (~1 block/CU), barriers gang-stall everything. Rollback to 32KB and fix
// structure: (1) per-wave private LDS slices -> ZERO barriers (A-frag rows
// are wave-exclusive); (2) fuse all three independent GEMMs into one
// mega-dispatch over 20992 wave-tiles, grid-stride + reg prefetch (T14);
// (3) B-frags global per-k0 (L2-hot, as in 114us R4). Launches 11 -> 8.

constexpr int T_ = 4, E_ = 4096, B_ = 2, D_ = 128, N_ = 384;
constexpr int EB = E_ * B_;                  // 8192 (e,b) pairs
constexpr int XSTRIDE_T = E_ * B_ * D_;      // floats between t-planes
constexpr int XROWS = T_ * EB;               // 32768 rows of x
constexpr int NROWS = N_ * N_ * B_;          // 294912 feats rows
constexpr int NCELLS = N_ * N_;              // 147456

constexpr int WT0 = XROWS / 16;              // 2048 wave-tiles (gemm1)
constexpr int WT1 = EB / 16;                 // 512  (ucontrib)
constexpr int WT2 = NROWS / 16;              // 18432 (feats)
constexpr int WTOT = WT0 + WT1 + WT2;        // 20992

typedef __attribute__((ext_vector_type(8))) short bf16x8;
typedef __attribute__((ext_vector_type(4))) float f32x4;
union BF8 { bf16x8 v; ushort u[8]; };

// workspace layout (float element offsets)
constexpr size_t OFF_WTG    = 0;                              // 16384
constexpr size_t OFF_WTL    = 16384;                          // 16384
constexpr size_t OFF_WTR    = 32768;                          // 16384
constexpr size_t OFF_BCOMB  = 49152;                          // 128
constexpr size_t OFF_BP     = 49280;                          // 128
constexpr size_t OFF_XMEAN  = 49408;                          // EB*D
constexpr size_t OFF_UC     = OFF_XMEAN + (size_t)EB * D_;    // EB*D
constexpr size_t OFF_WIN    = OFF_UC + (size_t)EB * D_;       // N*N ints
constexpr size_t OFF_BPACK  = OFF_WIN + (size_t)NCELLS;       // 16384 (64KB)
constexpr size_t OFF_BPACKG = OFF_BPACK + 16384;              // 16384
constexpr size_t OFF_BPACKR = OFF_BPACKG + 16384;             // 16384
constexpr size_t OFF_WGR    = OFF_BPACKR + 16384;             // 16384
constexpr size_t OFF_BGR    = OFF_WGR + 16384;                // 128
constexpr size_t WS_FLOATS  = OFF_BGR + 128;                  // ~9.5MB

static __device__ inline ushort f2bf(float x) {
  const uint u = __float_as_uint(x);
  return (ushort)((u + 0x7fffu + ((u >> 16) & 1u)) >> 16);
}
static __device__ inline float bf2f(ushort h) {
  return __uint_as_float(((uint)h) << 16);
}

// ---------------------------------------------------------------------------
// prep: W_comb halves (transposed), W_g transpose, bcomb, bp, winner init
// ---------------------------------------------------------------------------
__global__ __launch_bounds__(256) void prep_kernel(
    const float* __restrict__ W_f, const float* __restrict__ W_lin,
    const float* __restrict__ W_g, const float* __restrict__ b_lin,
    const float* __restrict__ b_f, const float* __restrict__ pad,
    float* __restrict__ WtG, float* __restrict__ WtL, float* __restrict__ WtR,
    float* __restrict__ bcomb, float* __restrict__ bp, int* __restrict__ winner) {
  const int o = blockIdx.x;    // 0..127
  const int c = threadIdx.x;   // 0..255

  for (int i = blockIdx.x * 256 + c; i < NCELLS; i += 128 * 256) winner[i] = -1;

  float acc = 0.f;
#pragma unroll 4
  for (int d = 0; d < D_; ++d) acc += W_f[o * D_ + d] * W_lin[d * (2 * D_) + c];

  if (c < D_) {
    WtL[c * D_ + o] = acc;
    WtG[c * D_ + o] = W_g[o * D_ + c];
  } else {
    WtR[(c - D_) * D_ + o] = acc;
  }

  __shared__ float red[256];
  red[c] = (c >= D_) ? acc : 0.f;
  __syncthreads();
  for (int s = 128; s > 0; s >>= 1) {
    if (c < s) red[c] += red[c + s];
    __syncthreads();
  }
  const float padsum = red[0];
  __syncthreads();
  red[c] = (c < D_) ? W_f[o * D_ + c] * b_lin[c] : 0.f;
  __syncthreads();
  for (int s = 128; s > 0; s >>= 1) {
    if (c < s) red[c] += red[c + s];
    __syncthreads();
  }
  if (c == 0) {
    const float bc = b_f[o] + red[0];
    bcomb[o] = bc;
    bp[o] = bc + pad[0] * padsum;
  }
}

// ---------------------------------------------------------------------------
// prepB: Wgr_kn[c*128+o] = sum_d WtR[d*128+o]*W_g[d*128+c]; bgr = WtR^T b_g
// ---------------------------------------------------------------------------
__global__ __launch_bounds__(128) void prepB_kernel(
    const float* __restrict__ WtR, const float* __restrict__ W_g,
    const float* __restrict__ b_g, float* __restrict__ Wgr_kn,
    float* __restrict__ bgr) {
  const int o = blockIdx.x;
  const int c = threadIdx.x;
  float acc = 0.f;
#pragma unroll 4
  for (int d = 0; d < D_; ++d) acc += WtR[d * D_ + o] * W_g[d * D_ + c];
  Wgr_kn[c * D_ + o] = acc;

  __shared__ float red[128];
  red[c] = WtR[c * D_ + o] * b_g[c];
  __syncthreads();
  for (int s = 64; s > 0; s >>= 1) {
    if (c < s) red[c] += red[c + s];
    __syncthreads();
  }
  if (c == 0) bgr[o] = red[0];
}

// ---------------------------------------------------------------------------
// prep2 (x3 fused): pack [k][n] fp32 weights into bf16 hi/lo B-fragments.
// grid (64, 3); blockIdx.y selects the weight.
// ---------------------------------------------------------------------------
__global__ __launch_bounds__(64) void prep2_kernel(
    const float* __restrict__ W0, const float* __restrict__ W1,
    const float* __restrict__ W2, ushort* __restrict__ B0,
    ushort* __restrict__ B1, ushort* __restrict__ B2) {
  const float* Wkn = blockIdx.y == 0 ? W0 : (blockIdx.y == 1 ? W1 : W2);
  ushort* Bpack    = blockIdx.y == 0 ? B0 : (blockIdx.y == 1 ? B1 : B2);
  const int fi = blockIdx.x;          // 0..63
  const int l = threadIdx.x;          // 0..63
  const int ishi = (fi >> 5) ^ 1;     // fi<32 -> hi
  const int k0 = (fi >> 3) & 3;
  const int n0 = fi & 7;
  const int o = n0 * 16 + (l & 15);
  const int kb = k0 * 32 + ((l >> 4) & 3) * 8;
  ushort* dst = Bpack + ((size_t)fi * 64 + l) * 8;
#pragma unroll
  for (int j = 0; j < 8; ++j) {
    const float w = Wkn[(size_t)(kb + j) * D_ + o];
    const ushort h = f2bf(w);
    if (ishi) {
      dst[j] = h;
    } else {
      dst[j] = f2bf(w - bf2f(h));
    }
  }
}

// ---------------------------------------------------------------------------
// scatter: last-e-wins per grid cell (deterministic via atomicMax on e)
// ---------------------------------------------------------------------------
__global__ __launch_bounds__(256) void scatter_kernel(
    const int* __restrict__ nodes, int* __restrict__ winner) {
  const int e = blockIdx.x * 256 + threadIdx.x;
  if (e < E_) {
    const int n0 = nodes[e * 2 + 0];
    const int n1 = nodes[e * 2 + 1];
    atomicMax(&winner[(n0 - 1) * N_ + (n1 - 1)], e);
  }
}

// ---------------------------------------------------------------------------
// mean over t of x: xmean[pair][c] = 0.25 * sum_t x[t*EB + pair][c]
// ---------------------------------------------------------------------------
__global__ __launch_bounds__(256) void mean_kernel(
    const float* __restrict__ x, float* __restrict__ xmean) {
  const int idx = blockIdx.x * 256 + threadIdx.x;   // 0 .. EB*32-1
  const int pair = idx >> 5;
  const int o4 = (idx & 31) * 4;
  const size_t base = (size_t)pair * D_ + o4;
  float4 s = *(const float4*)&x[base];
  const float4 v1 = *(const float4*)&x[base + (size_t)1 * XSTRIDE_T];
  const float4 v2 = *(const float4*)&x[base + (size_t)2 * XSTRIDE_T];
  const float4 v3 = *(const float4*)&x[base + (size_t)3 * XSTRIDE_T];
  s.x = (s.x + v1.x + v2.x + v3.x) * 0.25f;
  s.y = (s.y + v1.y + v2.y + v3.y) * 0.25f;
  s.z = (s.z + v1.z + v2.z + v3.z) * 0.25f;
  s.w = (s.w + v1.w + v2.w + v3.w) * 0.25f;
  *(float4*)&xmean[base] = s;
}

// ---------------------------------------------------------------------------
// mega_mfma: all three GEMMs in one dispatch. Unit = 16-row wave-tile.
//   t <  2048          : out_x = x @ WgT + b_g
//   2048 <= t < 2560   : uc    = xmean @ Wgr + bgr
//   t >= 2560          : out_feats = feats @ WcombL + bp
// Per-wave private 8KB LDS slice -> NO barriers. Grid-stride + reg prefetch.
// B-frags read per-k0 from L2-hot packs. MFMA 16x16x32 bf16 hi/lo split.
// ---------------------------------------------------------------------------
__global__ __launch_bounds__(256) void mega_mfma_kernel(
    const float* __restrict__ x, const float* __restrict__ xmean,
    const float* __restrict__ feats,
    const ushort* __restrict__ BpG, const ushort* __restrict__ BpR,
    const ushort* __restrict__ BpL,
    const float* __restrict__ b_g, const float* __restrict__ bgr,
    const float* __restrict__ bpv,
    float* __restrict__ out_x, float* __restrict__ ucv,
    float* __restrict__ out_feats) {
  __shared__ float lw[4 * 2048];          // 32 KB, 8KB per wave
  const int tid = threadIdx.x;
  const int wave = tid >> 6, lane = tid & 63;
  float* __restrict__ wlds = lw + wave * 2048;
  const int l15 = lane & 15;
  const int lh = (lane >> 4) & 3;
  const int asw = (l15 & 7) << 2;
  const int NW = gridDim.x * 4;

  int t = blockIdx.x * 4 + wave;
  float4 pf[8];
  {  // prologue prefetch
    const float* As; int r0;
    if (t < WT0)            { As = x;     r0 = t * 16; }
    else if (t < WT0 + WT1) { As = xmean; r0 = (t - WT0) * 16; }
    else                    { As = feats; r0 = (t - WT0 - WT1) * 16; }
#pragma unroll
    for (int j = 0; j < 8; ++j) {
      const int idx = j * 64 + lane;
      pf[j] = *(const float4*)&As[((size_t)r0 + (idx >> 5)) * D_ + (idx & 31) * 4];
    }
  }

  for (; t < WTOT; t += NW) {
    const ushort* Bp; const float* bias; float* Dst; int r0;
    if (t < WT0)            { Bp = BpG; bias = b_g; Dst = out_x;     r0 = t * 16; }
    else if (t < WT0 + WT1) { Bp = BpR; bias = bgr; Dst = ucv;       r0 = (t - WT0) * 16; }
    else                    { Bp = BpL; bias = bpv; Dst = out_feats; r0 = (t - WT0 - WT1) * 16; }

    // stage A (wave-local, swizzled); consumes pf
#pragma unroll
    for (int j = 0; j < 8; ++j) {
      const int idx = j * 64 + lane;
      const int row = idx >> 5, c4 = idx & 31;
      *(float4*)&wlds[(row * 128 + c4 * 4) ^ ((row & 7) << 2)] = pf[j];
    }

    // prefetch next tile (T14): issue now, consumed next iteration
    const int t2 = t + NW;
    if (t2 < WTOT) {
      const float* As; int r2;
      if (t2 < WT0)            { As = x;     r2 = t2 * 16; }
      else if (t2 < WT0 + WT1) { As = xmean; r2 = (t2 - WT0) * 16; }
      else                     { As = feats; r2 = (t2 - WT0 - WT1) * 16; }
#pragma unroll
      for (int j = 0; j < 8; ++j) {
        const int idx = j * 64 + lane;
        pf[j] = *(const float4*)&As[((size_t)r2 + (idx >> 5)) * D_ + (idx & 31) * 4];
      }
    }

    f32x4 acc[8];
#pragma unroll
    for (int n0 = 0; n0 < 8; ++n0) {
      const float b = bias[n0 * 16 + l15];
      acc[n0][0] = b; acc[n0][1] = b; acc[n0][2] = b; acc[n0][3] = b;
    }

    const bf16x8* __restrict__ bp8 = (const bf16x8*)Bp;
#pragma unroll
    for (int k0 = 0; k0 < 4; ++k0) {
      bf16x8 bh[8], bl[8];
#pragma unroll
      for (int n0 = 0; n0 < 8; ++n0) {
        bh[n0] = bp8[(size_t)((k0 * 8 + n0) * 64 + lane)];
        bl[n0] = bp8[(size_t)((32 + k0 * 8 + n0) * 64 + lane)];
      }
      const int base = l15 * 128 + lh * 8 + k0 * 32;
      const float4 a0 = *(const float4*)&wlds[(base + 0) ^ asw];
      const float4 a1 = *(const float4*)&wlds[(base + 4) ^ asw];
      const float xs[8] = {a0.x, a0.y, a0.z, a0.w, a1.x, a1.y, a1.z, a1.w};
      BF8 ah, al;
#pragma unroll
      for (int j = 0; j < 8; ++j) {
        const ushort h = f2bf(xs[j]);
        ah.u[j] = h;
        al.u[j] = f2bf(xs[j] - bf2f(h));
      }
#pragma unroll
      for (int n0 = 0; n0 < 8; ++n0) {
        acc[n0] = __builtin_amdgcn_mfma_f32_16x16x32_bf16(ah.v, bh[n0], acc[n0], 0, 0, 0);
        acc[n0] = __builtin_amdgcn_mfma_f32_16x16x32_bf16(al.v, bh[n0], acc[n0], 0, 0, 0);
        acc[n0] = __builtin_amdgcn_mfma_f32_16x16x32_bf16(ah.v, bl[n0], acc[n0], 0, 0, 0);
      }
    }

    // C transpose through the same wave-local slice (A fully consumed;
    // wave-lockstep LDS, in-order per wave -> no barrier needed)
#pragma unroll
    for (int n0 = 0; n0 < 8; ++n0) {
      const int col = n0 * 16 + l15;
#pragma unroll
      for (int i = 0; i < 4; ++i) {
        const int row = lh * 4 + i;
        wlds[(row * 128 + col) ^ ((row & 7) << 2)] = acc[n0][i];
      }
    }
#pragma unroll
    for (int j = 0; j < 8; ++j) {
      const int idx = j * 64 + lane;
      const int row = idx >> 5, c4 = idx & 31;
      const float4 v =
          *(const float4*)&wlds[(row * 128 + c4 * 4) ^ ((row & 7) << 2)];
      *(float4*)&Dst[((size_t)r0 + row) * D_ + c4 * 4] = v;
    }
  }
}

// ---------------------------------------------------------------------------
// fixup: winner rows: out_feats[cell*2+b][o] += uc[e*2+b][o] + bcomb[o]-bp[o]
// ---------------------------------------------------------------------------
__global__ __launch_bounds__(256) void fixup_kernel(
    const int* __restrict__ nodes, const int* __restrict__ winner,
    const float* __restrict__ uc, const float* __restrict__ bcomb,
    const float* __restrict__ bp, float* __restrict__ out_feats) {
  const int e = blockIdx.x;
  const int n0 = nodes[e * 2 + 0] - 1;
  const int n1 = nodes[e * 2 + 1] - 1;
  const int cell = n0 * N_ + n1;
  if (winner[cell] != e) return;
  const int t = threadIdx.x;
  const int b = t >> 7, o = t & 127;
  out_feats[((size_t)cell * 2 + b) * D_ + o] +=
      uc[((size_t)e * 2 + b) * D_ + o] + bcomb[o] - bp[o];
}

// ---------------------------------------------------------------------------
// gather_add: out_x[t,e,b,:] += out_feats[n0-1, n1-1, b, :]
// ---------------------------------------------------------------------------
__global__ __launch_bounds__(256) void gather_add_kernel(
    const int* __restrict__ nodes, const float* __restrict__ out_feats,
    float* __restrict__ out_x) {
  const int e = blockIdx.x;
  const int tid = threadIdx.x;
  const int b = tid >> 7, o = tid & 127;
  const int n0 = nodes[((size_t)b * E_ + e) * 2 + 0] - 1;
  const int n1 = nodes[((size_t)b * E_ + e) * 2 + 1] - 1;
  const float fs = out_feats[(((size_t)n0 * N_ + n1) * B_ + b) * D_ + o];
#pragma unroll
  for (int t = 0; t < T_; ++t)
    out_x[(((size_t)t * E_ + e) * B_ + b) * D_ + o] += fs;
}

// ---------------------------------------------------------------------------
extern "C" void kernel_launch(void* const* d_in, const int* in_sizes, int n_in,
                              void* d_out, int out_size, void* d_ws, size_t ws_size,
                              hipStream_t stream) {
  const float* x      = (const float*)d_in[0];
  const float* feats  = (const float*)d_in[1];
  const int*   nodes  = (const int*)d_in[2];
  const float* pad    = (const float*)d_in[5];
  const float* W_g    = (const float*)d_in[6];
  const float* b_g    = (const float*)d_in[7];
  const float* W_lin  = (const float*)d_in[8];
  const float* b_lin  = (const float*)d_in[9];
  const float* W_f    = (const float*)d_in[10];
  const float* b_f    = (const float*)d_in[11];

  float* out_x     = (float*)d_out;                       // T*E*B*D
  float* out_feats = out_x + (size_t)T_ * E_ * B_ * D_;   // N*N*B*D

  if (ws_size < WS_FLOATS * sizeof(float) + 16) return;

  float*  wsf    = (float*)d_ws;
  float*  WtG    = wsf + OFF_WTG;
  float*  WtL    = wsf + OFF_WTL;
  float*  WtR    = wsf + OFF_WTR;
  float*  bcomb  = wsf + OFF_BCOMB;
  float*  bpv    = wsf + OFF_BP;
  float*  xmean  = wsf + OFF_XMEAN;
  float*  uc     = wsf + OFF_UC;
  int*    win    = (int*)(wsf + OFF_WIN);
  ushort* Bpack  = (ushort*)(wsf + OFF_BPACK);
  ushort* BpackG = (ushort*)(wsf + OFF_BPACKG);
  ushort* BpackR = (ushort*)(wsf + OFF_BPACKR);
  float*  WgrKn  = wsf + OFF_WGR;
  float*  bgr    = wsf + OFF_BGR;

  prep_kernel<<<dim3(128), dim3(256), 0, stream>>>(W_f, W_lin, W_g, b_lin, b_f,
                                                   pad, WtG, WtL, WtR, bcomb,
                                                   bpv, win);
  prepB_kernel<<<dim3(128), dim3(128), 0, stream>>>(WtR, W_g, b_g, WgrKn, bgr);
  prep2_kernel<<<dim3(64, 3), dim3(64), 0, stream>>>(WtL, WtG, WgrKn, Bpack,
                                                     BpackG, BpackR);
  scatter_kernel<<<dim3(E_ / 256), dim3(256), 0, stream>>>(nodes, win);
  mean_kernel<<<dim3(EB * 32 / 256), dim3(256), 0, stream>>>(x, xmean);

  mega_mfma_kernel<<<dim3(1024), dim3(256), 0, stream>>>(
      x, xmean, feats, BpackG, BpackR, Bpack, b_g, bgr, bpv, out_x, uc,
      out_feats);
  fixup_kernel<<<dim3(E_), dim3(256), 0, stream>>>(nodes, win, uc, bcomb, bpv,
                                                   out_feats);
  gather_add_kernel<<<dim3(E_), dim3(256), 0, stream>>>(nodes, out_feats,
                                                        out_x);
}

// Round 8
// 419.613 us; speedup vs baseline: 1.1500x; 1.0576x over previous
//
#include <hip/hip_runtime.h>
#include <hip/hip_bf16.h>

// R7. R6 mega (wave-private, grid-stride, 1024 blocks) = 188us: WRITE 319MB
// (1.85x ideal -> thin interleaved per-wave write streams amplify; R4's fat
// block-cooperative bursts gave exactly-ideal WRITE), occ 22%, all pipes idle.
// Fix: block-cooperative 32-row tile in ONE 16KB LDS buffer, reg-staged
// prefetch of next tile issued right after stage-write (latency hides under
// compute), grid-stride 1024 blocks w/ XCD swizzle, 2x2 wave split of the
// 32x128 output (48 MFMA/wave/tile, half the B L2-loads). 4 barriers/iter.
// launch_bounds(256,4) caps VGPR at 128 (R5 lesson: 148 VGPR -> 1 block/CU).
// NOTE: ~230us of dur_us is fixed harness restore/poison overhead (consistent
// across R4-R6); controllable kernel time is the target.

constexpr int T_ = 4, E_ = 4096, B_ = 2, D_ = 128, N_ = 384;
constexpr int EB = E_ * B_;                  // 8192 (e,b) pairs
constexpr int XSTRIDE_T = E_ * B_ * D_;      // floats between t-planes
constexpr int XROWS = T_ * EB;               // 32768 rows of x
constexpr int NROWS = N_ * N_ * B_;          // 294912 feats rows
constexpr int NCELLS = N_ * N_;              // 147456

typedef __attribute__((ext_vector_type(8))) short bf16x8;
typedef __attribute__((ext_vector_type(4))) float f32x4;
union BF8 { bf16x8 v; ushort u[8]; };

// workspace layout (float element offsets)
constexpr size_t OFF_WTG    = 0;                              // 16384
constexpr size_t OFF_WTL    = 16384;                          // 16384
constexpr size_t OFF_WTR    = 32768;                          // 16384
constexpr size_t OFF_BCOMB  = 49152;                          // 128
constexpr size_t OFF_BP     = 49280;                          // 128
constexpr size_t OFF_XMEAN  = 49408;                          // EB*D
constexpr size_t OFF_UC     = OFF_XMEAN + (size_t)EB * D_;    // EB*D
constexpr size_t OFF_WIN    = OFF_UC + (size_t)EB * D_;       // N*N ints
constexpr size_t OFF_BPACK  = OFF_WIN + (size_t)NCELLS;       // 16384 (64KB)
constexpr size_t OFF_BPACKG = OFF_BPACK + 16384;              // 16384
constexpr size_t OFF_BPACKR = OFF_BPACKG + 16384;             // 16384
constexpr size_t OFF_WGR    = OFF_BPACKR + 16384;             // 16384
constexpr size_t OFF_BGR    = OFF_WGR + 16384;                // 128
constexpr size_t WS_FLOATS  = OFF_BGR + 128;                  // ~9.5MB

static __device__ inline ushort f2bf(float x) {
  const uint u = __float_as_uint(x);
  return (ushort)((u + 0x7fffu + ((u >> 16) & 1u)) >> 16);
}
static __device__ inline float bf2f(ushort h) {
  return __uint_as_float(((uint)h) << 16);
}

// ---------------------------------------------------------------------------
// prep: W_comb halves (transposed), W_g transpose, bcomb, bp, winner init
// ---------------------------------------------------------------------------
__global__ __launch_bounds__(256) void prep_kernel(
    const float* __restrict__ W_f, const float* __restrict__ W_lin,
    const float* __restrict__ W_g, const float* __restrict__ b_lin,
    const float* __restrict__ b_f, const float* __restrict__ pad,
    float* __restrict__ WtG, float* __restrict__ WtL, float* __restrict__ WtR,
    float* __restrict__ bcomb, float* __restrict__ bp, int* __restrict__ winner) {
  const int o = blockIdx.x;    // 0..127
  const int c = threadIdx.x;   // 0..255

  for (int i = blockIdx.x * 256 + c; i < NCELLS; i += 128 * 256) winner[i] = -1;

  float acc = 0.f;
#pragma unroll 4
  for (int d = 0; d < D_; ++d) acc += W_f[o * D_ + d] * W_lin[d * (2 * D_) + c];

  if (c < D_) {
    WtL[c * D_ + o] = acc;
    WtG[c * D_ + o] = W_g[o * D_ + c];
  } else {
    WtR[(c - D_) * D_ + o] = acc;
  }

  __shared__ float red[256];
  red[c] = (c >= D_) ? acc : 0.f;
  __syncthreads();
  for (int s = 128; s > 0; s >>= 1) {
    if (c < s) red[c] += red[c + s];
    __syncthreads();
  }
  const float padsum = red[0];
  __syncthreads();
  red[c] = (c < D_) ? W_f[o * D_ + c] * b_lin[c] : 0.f;
  __syncthreads();
  for (int s = 128; s > 0; s >>= 1) {
    if (c < s) red[c] += red[c + s];
    __syncthreads();
  }
  if (c == 0) {
    const float bc = b_f[o] + red[0];
    bcomb[o] = bc;
    bp[o] = bc + pad[0] * padsum;
  }
}

// ---------------------------------------------------------------------------
// prepB: Wgr_kn[c*128+o] = sum_d WtR[d*128+o]*W_g[d*128+c]; bgr = WtR^T b_g
// ---------------------------------------------------------------------------
__global__ __launch_bounds__(128) void prepB_kernel(
    const float* __restrict__ WtR, const float* __restrict__ W_g,
    const float* __restrict__ b_g, float* __restrict__ Wgr_kn,
    float* __restrict__ bgr) {
  const int o = blockIdx.x;
  const int c = threadIdx.x;
  float acc = 0.f;
#pragma unroll 4
  for (int d = 0; d < D_; ++d) acc += WtR[d * D_ + o] * W_g[d * D_ + c];
  Wgr_kn[c * D_ + o] = acc;

  __shared__ float red[128];
  red[c] = WtR[c * D_ + o] * b_g[c];
  __syncthreads();
  for (int s = 64; s > 0; s >>= 1) {
    if (c < s) red[c] += red[c + s];
    __syncthreads();
  }
  if (c == 0) bgr[o] = red[0];
}

// ---------------------------------------------------------------------------
// prep2 (x3 fused): pack [k][n] fp32 weights into bf16 hi/lo B-fragments.
// ---------------------------------------------------------------------------
__global__ __launch_bounds__(64) void prep2_kernel(
    const float* __restrict__ W0, const float* __restrict__ W1,
    const float* __restrict__ W2, ushort* __restrict__ B0,
    ushort* __restrict__ B1, ushort* __restrict__ B2) {
  const float* Wkn = blockIdx.y == 0 ? W0 : (blockIdx.y == 1 ? W1 : W2);
  ushort* Bpack    = blockIdx.y == 0 ? B0 : (blockIdx.y == 1 ? B1 : B2);
  const int fi = blockIdx.x;          // 0..63
  const int l = threadIdx.x;          // 0..63
  const int ishi = (fi >> 5) ^ 1;     // fi<32 -> hi
  const int k0 = (fi >> 3) & 3;
  const int n0 = fi & 7;
  const int o = n0 * 16 + (l & 15);
  const int kb = k0 * 32 + ((l >> 4) & 3) * 8;
  ushort* dst = Bpack + ((size_t)fi * 64 + l) * 8;
#pragma unroll
  for (int j = 0; j < 8; ++j) {
    const float w = Wkn[(size_t)(kb + j) * D_ + o];
    const ushort h = f2bf(w);
    if (ishi) {
      dst[j] = h;
    } else {
      dst[j] = f2bf(w - bf2f(h));
    }
  }
}

// ---------------------------------------------------------------------------
// scatter: last-e-wins per grid cell (deterministic via atomicMax on e)
// ---------------------------------------------------------------------------
__global__ __launch_bounds__(256) void scatter_kernel(
    const int* __restrict__ nodes, int* __restrict__ winner) {
  const int e = blockIdx.x * 256 + threadIdx.x;
  if (e < E_) {
    const int n0 = nodes[e * 2 + 0];
    const int n1 = nodes[e * 2 + 1];
    atomicMax(&winner[(n0 - 1) * N_ + (n1 - 1)], e);
  }
}

// ---------------------------------------------------------------------------
// mean over t of x
// ---------------------------------------------------------------------------
__global__ __launch_bounds__(256) void mean_kernel(
    const float* __restrict__ x, float* __restrict__ xmean) {
  const int idx = blockIdx.x * 256 + threadIdx.x;   // 0 .. EB*32-1
  const int pair = idx >> 5;
  const int o4 = (idx & 31) * 4;
  const size_t base = (size_t)pair * D_ + o4;
  float4 s = *(const float4*)&x[base];
  const float4 v1 = *(const float4*)&x[base + (size_t)1 * XSTRIDE_T];
  const float4 v2 = *(const float4*)&x[base + (size_t)2 * XSTRIDE_T];
  const float4 v3 = *(const float4*)&x[base + (size_t)3 * XSTRIDE_T];
  s.x = (s.x + v1.x + v2.x + v3.x) * 0.25f;
  s.y = (s.y + v1.y + v2.y + v3.y) * 0.25f;
  s.z = (s.z + v1.z + v2.z + v3.z) * 0.25f;
  s.w = (s.w + v1.w + v2.w + v3.w) * 0.25f;
  *(float4*)&xmean[base] = s;
}

// ---------------------------------------------------------------------------
// mega2: all three GEMMs, block-cooperative 32-row tiles, single 16KB LDS
// buffer, reg-staged prefetch pipeline, 2x2 wave split of the output.
//   t <  1024          : out_x = x @ WgT + b_g
//   1024 <= t < 1280   : uc    = xmean @ Wgr + bgr
//   t >= 1280          : out_feats = feats @ WcombL + bp
// ---------------------------------------------------------------------------
__global__ __launch_bounds__(256, 4) void mega2_kernel(
    const float* __restrict__ x, const float* __restrict__ xmean,
    const float* __restrict__ feats,
    const ushort* __restrict__ BpG, const ushort* __restrict__ BpR,
    const ushort* __restrict__ BpL,
    const float* __restrict__ b_g, const float* __restrict__ bgr,
    const float* __restrict__ bpv,
    float* __restrict__ out_x, float* __restrict__ ucv,
    float* __restrict__ out_feats) {
  __shared__ float lw[4096];               // 16 KB: 32 rows x 128, swizzled
  const int tid = threadIdx.x;
  const int wave = tid >> 6, lane = tid & 63;
  const int l15 = lane & 15, lh = (lane >> 4) & 3;
  const int rh = (wave & 1) * 16;          // row half owned by this wave
  const int nb = (wave >> 1) * 4;          // n0 base (col half)
  constexpr int GRID = 1024;
  constexpr int TT0 = XROWS / 32;                 // 1024
  constexpr int TT1 = EB / 32;                    // 256
  constexpr int TTOT = TT0 + TT1 + NROWS / 32;    // 10496

  const int bid = blockIdx.x;
  int t = (bid & 7) * (GRID / 8) + (bid >> 3);    // XCD swizzle (1024%8==0)

  float4 pf[4];
  {  // prologue prefetch A(t)
    const float* As; int r0;
    if (t < TT0)            { As = x;     r0 = t * 32; }
    else if (t < TT0 + TT1) { As = xmean; r0 = (t - TT0) * 32; }
    else                    { As = feats; r0 = (t - TT0 - TT1) * 32; }
#pragma unroll
    for (int r = 0; r < 4; ++r) {
      const int idx = r * 256 + tid;
      pf[r] = *(const float4*)&As[((size_t)r0 + (idx >> 5)) * D_ + (idx & 31) * 4];
    }
  }

  while (t < TTOT) {
    const ushort* Bp; const float* bias; float* Dst; int r0;
    if (t < TT0)            { Bp = BpG; bias = b_g; Dst = out_x;     r0 = t * 32; }
    else if (t < TT0 + TT1) { Bp = BpR; bias = bgr; Dst = ucv;       r0 = (t - TT0) * 32; }
    else                    { Bp = BpL; bias = bpv; Dst = out_feats; r0 = (t - TT0 - TT1) * 32; }

    __syncthreads();   // (d) buf free: prev tile's C-store LDS reads done
#pragma unroll
    for (int r = 0; r < 4; ++r) {   // stage A(t) regs -> swizzled LDS
      const int idx = r * 256 + tid;
      const int row = idx >> 5, c4 = idx & 31;
      *(float4*)&lw[(row * 128 + c4 * 4) ^ ((row & 7) << 2)] = pf[r];
    }
    const int tn = t + GRID;
    if (tn < TTOT) {   // async prefetch A(tn); flies during compute
      const float* As; int r2;
      if (tn < TT0)            { As = x;     r2 = tn * 32; }
      else if (tn < TT0 + TT1) { As = xmean; r2 = (tn - TT0) * 32; }
      else                     { As = feats; r2 = (tn - TT0 - TT1) * 32; }
#pragma unroll
      for (int r = 0; r < 4; ++r) {
        const int idx = r * 256 + tid;
        pf[r] = *(const float4*)&As[((size_t)r2 + (idx >> 5)) * D_ + (idx & 31) * 4];
      }
    }
    __syncthreads();   // (a) A(t) visible to all waves

    f32x4 acc[4];
#pragma unroll
    for (int n0 = 0; n0 < 4; ++n0) {
      const float b = bias[(nb + n0) * 16 + l15];
      acc[n0][0] = b; acc[n0][1] = b; acc[n0][2] = b; acc[n0][3] = b;
    }
    const bf16x8* __restrict__ bp8 = (const bf16x8*)Bp;
#pragma unroll
    for (int k0 = 0; k0 < 4; ++k0) {
      bf16x8 bh[4], bl[4];
#pragma unroll
      for (int n0 = 0; n0 < 4; ++n0) {
        bh[n0] = bp8[(size_t)((k0 * 8 + nb + n0) * 64 + lane)];
        bl[n0] = bp8[(size_t)((32 + k0 * 8 + nb + n0) * 64 + lane)];
      }
      const int row = rh + l15;
      const int fb = row * 128 + lh * 8 + k0 * 32;
      const int sw = (row & 7) << 2;
      const float4 a0 = *(const float4*)&lw[(fb + 0) ^ sw];
      const float4 a1 = *(const float4*)&lw[(fb + 4) ^ sw];
      const float xs[8] = {a0.x, a0.y, a0.z, a0.w, a1.x, a1.y, a1.z, a1.w};
      BF8 ah, al;
#pragma unroll
      for (int j = 0; j < 8; ++j) {
        const ushort h = f2bf(xs[j]);
        ah.u[j] = h;
        al.u[j] = f2bf(xs[j] - bf2f(h));
      }
#pragma unroll
      for (int n0 = 0; n0 < 4; ++n0) {
        acc[n0] = __builtin_amdgcn_mfma_f32_16x16x32_bf16(ah.v, bh[n0], acc[n0], 0, 0, 0);
        acc[n0] = __builtin_amdgcn_mfma_f32_16x16x32_bf16(al.v, bh[n0], acc[n0], 0, 0, 0);
        acc[n0] = __builtin_amdgcn_mfma_f32_16x16x32_bf16(ah.v, bl[n0], acc[n0], 0, 0, 0);
      }
    }
    __syncthreads();   // (b) all waves done reading A(t)

#pragma unroll
    for (int n0 = 0; n0 < 4; ++n0) {   // C -> swizzled LDS (transpose)
      const int col = (nb + n0) * 16 + l15;
#pragma unroll
      for (int i = 0; i < 4; ++i) {
        const int row = rh + lh * 4 + i;
        lw[(row * 128 + col) ^ ((row & 7) << 2)] = acc[n0][i];
      }
    }
    __syncthreads();   // (c) C visible
#pragma unroll
    for (int r = 0; r < 4; ++r) {      // fully coalesced stores
      const int idx = r * 256 + tid;
      const int row = idx >> 5, c4 = idx & 31;
      const float4 v =
          *(const float4*)&lw[(row * 128 + c4 * 4) ^ ((row & 7) << 2)];
      *(float4*)&Dst[((size_t)r0 + row) * D_ + c4 * 4] = v;
    }
    t = tn;
  }
}

// ---------------------------------------------------------------------------
// fixup: winner rows: out_feats[cell*2+b][o] += uc[e*2+b][o] + bcomb[o]-bp[o]
// ---------------------------------------------------------------------------
__global__ __launch_bounds__(256) void fixup_kernel(
    const int* __restrict__ nodes, const int* __restrict__ winner,
    const float* __restrict__ uc, const float* __restrict__ bcomb,
    const float* __restrict__ bp, float* __restrict__ out_feats) {
  const int e = blockIdx.x;
  const int n0 = nodes[e * 2 + 0] - 1;
  const int n1 = nodes[e * 2 + 1] - 1;
  const int cell = n0 * N_ + n1;
  if (winner[cell] != e) return;
  const int t = threadIdx.x;
  const int b = t >> 7, o = t & 127;
  out_feats[((size_t)cell * 2 + b) * D_ + o] +=
      uc[((size_t)e * 2 + b) * D_ + o] + bcomb[o] - bp[o];
}

// ---------------------------------------------------------------------------
// gather_add: out_x[t,e,b,:] += out_feats[n0-1, n1-1, b, :]
// ---------------------------------------------------------------------------
__global__ __launch_bounds__(256) void gather_add_kernel(
    const int* __restrict__ nodes, const float* __restrict__ out_feats,
    float* __restrict__ out_x) {
  const int e = blockIdx.x;
  const int tid = threadIdx.x;
  const int b = tid >> 7, o = tid & 127;
  const int n0 = nodes[((size_t)b * E_ + e) * 2 + 0] - 1;
  const int n1 = nodes[((size_t)b * E_ + e) * 2 + 1] - 1;
  const float fs = out_feats[(((size_t)n0 * N_ + n1) * B_ + b) * D_ + o];
#pragma unroll
  for (int t = 0; t < T_; ++t)
    out_x[(((size_t)t * E_ + e) * B_ + b) * D_ + o] += fs;
}

// ---------------------------------------------------------------------------
extern "C" void kernel_launch(void* const* d_in, const int* in_sizes, int n_in,
                              void* d_out, int out_size, void* d_ws, size_t ws_size,
                              hipStream_t stream) {
  const float* x      = (const float*)d_in[0];
  const float* feats  = (const float*)d_in[1];
  const int*   nodes  = (const int*)d_in[2];
  const float* pad    = (const float*)d_in[5];
  const float* W_g    = (const float*)d_in[6];
  const float* b_g    = (const float*)d_in[7];
  const float* W_lin  = (const float*)d_in[8];
  const float* b_lin  = (const float*)d_in[9];
  const float* W_f    = (const float*)d_in[10];
  const float* b_f    = (const float*)d_in[11];

  float* out_x     = (float*)d_out;                       // T*E*B*D
  float* out_feats = out_x + (size_t)T_ * E_ * B_ * D_;   // N*N*B*D

  if (ws_size < WS_FLOATS * sizeof(float) + 16) return;

  float*  wsf    = (float*)d_ws;
  float*  WtG    = wsf + OFF_WTG;
  float*  WtL    = wsf + OFF_WTL;
  float*  WtR    = wsf + OFF_WTR;
  float*  bcomb  = wsf + OFF_BCOMB;
  float*  bpv    = wsf + OFF_BP;
  float*  xmean  = wsf + OFF_XMEAN;
  float*  uc     = wsf + OFF_UC;
  int*    win    = (int*)(wsf + OFF_WIN);
  ushort* Bpack  = (ushort*)(wsf + OFF_BPACK);
  ushort* BpackG = (ushort*)(wsf + OFF_BPACKG);
  ushort* BpackR = (ushort*)(wsf + OFF_BPACKR);
  float*  WgrKn  = wsf + OFF_WGR;
  float*  bgr    = wsf + OFF_BGR;

  prep_kernel<<<dim3(128), dim3(256), 0, stream>>>(W_f, W_lin, W_g, b_lin, b_f,
                                                   pad, WtG, WtL, WtR, bcomb,
                                                   bpv, win);
  prepB_kernel<<<dim3(128), dim3(128), 0, stream>>>(WtR, W_g, b_g, WgrKn, bgr);
  prep2_kernel<<<dim3(64, 3), dim3(64), 0, stream>>>(WtL, WtG, WgrKn, Bpack,
                                                     BpackG, BpackR);
  scatter_kernel<<<dim3(E_ / 256), dim3(256), 0, stream>>>(nodes, win);
  mean_kernel<<<dim3(EB * 32 / 256), dim3(256), 0, stream>>>(x, xmean);

  mega2_kernel<<<dim3(1024), dim3(256), 0, stream>>>(
      x, xmean, feats, BpackG, BpackR, Bpack, b_g, bgr, bpv, out_x, uc,
      out_feats);
  fixup_kernel<<<dim3(E_), dim3(256), 0, stream>>>(nodes, win, uc, bcomb, bpv,
                                                   out_feats);
  gather_add_kernel<<<dim3(E_), dim3(256), 0, stream>>>(nodes, out_feats,
                                                        out_x);
}